// Round 11
// baseline (173.456 us; speedup 1.0000x reference)
//
#include <hip/hip_runtime.h>
#include <stdint.h>

typedef unsigned short u16;
typedef float  f32x4  __attribute__((ext_vector_type(4)));
typedef __bf16 bf16x8 __attribute__((ext_vector_type(8)));
typedef __bf16 bf16x4 __attribute__((ext_vector_type(4)));
typedef unsigned short u16x8 __attribute__((ext_vector_type(8)));
typedef unsigned short u16x4v __attribute__((ext_vector_type(4)));

#define S_LEN 2048
#define E_DIM 2048
#define HD    128
#define QH    16
#define KVH   4
#define KVD   512
#define NQKV  3072
#define QK_SCALE 0.08838834764831845f  // 1/sqrt(128)

#define AS1 __attribute__((address_space(1)))
#define AS3 __attribute__((address_space(3)))

__device__ __forceinline__ u16 f2bf(float f) {
  union { float f; uint32_t u; } v; v.f = f;
  return (u16)((v.u + 0x7FFFu + ((v.u >> 16) & 1u)) >> 16);
}
__device__ __forceinline__ float bf2f(u16 b) {
  union { uint32_t u; float f; } v; v.u = ((uint32_t)b) << 16;
  return v.f;
}

// ---------------- fused cast fp32 -> bf16 for all 5 tensors ----------------
__global__ void cast_all_kernel(const float* __restrict__ x, const float* __restrict__ Wq,
                                const float* __restrict__ Wk, const float* __restrict__ Wv,
                                const float* __restrict__ Wo,
                                u16* __restrict__ xb, u16* __restrict__ Wcat,
                                u16* __restrict__ Wob) {
  int i = blockIdx.x * blockDim.x + threadIdx.x;
  const float* src; u16* dst;
  if (i < (1 << 20))                       { src = x  + (size_t)i * 4;  dst = xb + (size_t)i * 4; }
  else if (i < (2 << 20))                  { size_t j = i - (1 << 20);  src = Wq + j * 4; dst = Wcat + j * 4; }
  else if (i < (2 << 20) + (1 << 18))      { size_t j = i - (2 << 20);  src = Wk + j * 4; dst = Wcat + (size_t)E_DIM * E_DIM + j * 4; }
  else if (i < (2 << 20) + (2 << 18))      { size_t j = i - (2 << 20) - (1 << 18); src = Wv + j * 4; dst = Wcat + (size_t)(E_DIM + KVD) * E_DIM + j * 4; }
  else                                     { size_t j = i - (2 << 20) - (2 << 18); src = Wo + j * 4; dst = Wob + j * 4; }
  float4 f = *reinterpret_cast<const float4*>(src);
  u16x4v o;
  o[0] = f2bf(f.x); o[1] = f2bf(f.y); o[2] = f2bf(f.z); o[3] = f2bf(f.w);
  *reinterpret_cast<u16x4v*>(dst) = o;
}

// ---------------- GEMM: C[M,N] = A[M,K] * B[N,K]^T (+bias), bf16 in ----------
// 128x128 tile, BK=64, 512 threads = 8 waves (2x4, each owns 64x32).
template<bool BIAS, bool OBF16>
__global__ __launch_bounds__(512) void gemm_bt_kernel(
    const u16* __restrict__ A, const u16* __restrict__ B,
    void* __restrict__ Cv, const float* __restrict__ bias,
    int M, int N, int K)
{
  __shared__ u16 As[2][128 * 64];
  __shared__ u16 Bs[2][128 * 64];

  const int tid  = threadIdx.x;
  const int lane = tid & 63;
  const int wid  = tid >> 6;           // 0..7
  const int wr   = (wid >> 2) * 64;    // 2 wave-rows
  const int wc   = (wid & 3) * 32;     // 4 wave-cols
  const int lr   = lane & 15;
  const int kg   = lane >> 4;
  const int sw   = lr & 7;

  const int bm = blockIdx.y * 128;
  const int bn = blockIdx.x * 128;

  f32x4 acc[4][2];
  #pragma unroll
  for (int r = 0; r < 4; ++r)
    #pragma unroll
    for (int c = 0; c < 2; ++c) acc[r][c] = (f32x4){0.f, 0.f, 0.f, 0.f};

  const int srow   = wid * 8 + (lane >> 3);
  const int schunk = (lane & 7) ^ (lane >> 3);

  const u16* gA = A + (size_t)(bm + srow) * K + schunk * 8;
  const u16* gB = B + (size_t)(bn + srow) * K + schunk * 8;

  auto stage = [&](int buf, int kt) {
    #pragma unroll
    for (int i = 0; i < 2; ++i) {
      __builtin_amdgcn_global_load_lds(
          (const AS1 void*)(gA + (size_t)i * 64 * K + kt),
          (AS3 void*)(&As[buf][(wid*8 + i*64) * 64]), 16, 0, 0);
      __builtin_amdgcn_global_load_lds(
          (const AS1 void*)(gB + (size_t)i * 64 * K + kt),
          (AS3 void*)(&Bs[buf][(wid*8 + i*64) * 64]), 16, 0, 0);
    }
  };

  stage(0, 0);
  __syncthreads();

  int cur = 0;
  for (int kt = 0; kt < K; kt += 64) {
    if (kt + 64 < K) stage(cur ^ 1, kt + 64);
    #pragma unroll
    for (int kk = 0; kk < 2; ++kk) {
      bf16x8 af[4], bfr[2];
      #pragma unroll
      for (int r = 0; r < 4; ++r)
        af[r] = *reinterpret_cast<const bf16x8*>(
            &As[cur][(wr + r*16 + lr)*64 + ((kk*4 + kg) ^ sw)*8]);
      #pragma unroll
      for (int c = 0; c < 2; ++c)
        bfr[c] = *reinterpret_cast<const bf16x8*>(
            &Bs[cur][(wc + c*16 + lr)*64 + ((kk*4 + kg) ^ sw)*8]);
      #pragma unroll
      for (int r = 0; r < 4; ++r)
        #pragma unroll
        for (int c = 0; c < 2; ++c)
          acc[r][c] = __builtin_amdgcn_mfma_f32_16x16x32_bf16(af[r], bfr[c], acc[r][c], 0, 0, 0);
    }
    __syncthreads();
    cur ^= 1;
  }

  const int crow = kg * 4;
  #pragma unroll
  for (int r = 0; r < 4; ++r) {
    #pragma unroll
    for (int c = 0; c < 2; ++c) {
      int gr = bm + wr + r*16 + crow;
      int gc = bn + wc + c*16 + lr;
      float badd = BIAS ? bias[gc] : 0.0f;
      #pragma unroll
      for (int reg = 0; reg < 4; ++reg) {
        float v = acc[r][c][reg] + badd;
        if constexpr (OBF16)
          ((u16*)Cv)[(size_t)(gr + reg)*N + gc] = f2bf(v);
        else
          ((float*)Cv)[(size_t)(gr + reg)*N + gc] = v;
      }
    }
  }
}

// ---------------- RoPE + split qkv_bf16 -> q_bf16 (scaled), k_bf16 -------------
__global__ void rope_split_kernel(const u16* __restrict__ qkv,
                                  u16* __restrict__ qb, u16* __restrict__ kb) {
  int idx = blockIdx.x * blockDim.x + threadIdx.x;
  int s  = idx / 1280;
  int cp = idx - s * 1280;
  int col = cp * 2;
  const u16* src = qkv + (size_t)s * NQKV + col;
  float x0 = bf2f(src[0]), x1 = bf2f(src[1]);
  int p = (col & 127) >> 1;
  float inv = exp2f((float)p * (-13.287712379549449f / 64.0f));
  float ang = (float)s * inv;
  float sn, cs;
  sincosf(ang, &sn, &cs);
  float o0 = x0 * cs - x1 * sn;
  float o1 = x0 * sn + x1 * cs;
  if (col < E_DIM) {
    o0 *= QK_SCALE; o1 *= QK_SCALE;
    qb[(size_t)s * E_DIM + col]     = f2bf(o0);
    qb[(size_t)s * E_DIM + col + 1] = f2bf(o1);
  } else {
    kb[(size_t)s * KVD + (col - E_DIM)]     = f2bf(o0);
    kb[(size_t)s * KVD + (col - E_DIM) + 1] = f2bf(o1);
  }
}

// ---------------- V transpose: qkv bf16 v-block (S x 512) -> vT (512 x S) ------
__global__ void transpose_v_kernel(const u16* __restrict__ qkv, u16* __restrict__ vT) {
  __shared__ u16 tile[32][33];
  const int sbase = blockIdx.x * 32;
  const int cbase = blockIdx.y * 32;
  const int tx = threadIdx.x;
  const int ty = threadIdx.y;
  #pragma unroll
  for (int i = 0; i < 32; i += 8)
    tile[ty + i][tx] = qkv[(size_t)(sbase + ty + i) * NQKV + (E_DIM + KVD) + cbase + tx];
  __syncthreads();
  #pragma unroll
  for (int i = 0; i < 32; i += 8)
    vT[(size_t)(cbase + ty + i) * S_LEN + sbase + tx] = tile[tx][ty + i];
}

// ---------------- Flash attention (causal, GQA 4:1), 2-head blocks -------------
// 256 blocks = 1/CU. Block: heads {2hp, 2hp+1} (same kvh) x 64 q-rows; wave w:
// head = 2hp+(w&1), rows (w>>1)*32 (two 16-row groups). K/V staged ONCE serve
// both heads; each K/V fragment read feeds 2 MFMAs (one per row-group).
// Balance: phases qtA=(x>>3)&31 then qtB=31-qtA -> exactly 33 tiles per block.
// r4-validated pipeline: reg-staged K/V dbuf (XOR swizzle), 1 barrier/tile,
// swapped QK^T in-register softmax, defer-max THR=8, Ps P-routing.
__global__ __launch_bounds__(256, 1) void attn_kernel(
    const u16* __restrict__ Q, const u16* __restrict__ Kc,
    const u16* __restrict__ VT, u16* __restrict__ Out)
{
  __shared__ u16 Ks[2][64 * 128];   // [kv][d] 16KB x2
  __shared__ u16 VTs[2][128 * 64];  // [d][kv] 16KB x2
  __shared__ u16 Ps[4][32 * 72];    // per-wave P (32 rows), 18.4KB

  const int x    = blockIdx.x;      // 256 blocks: 8 head-pairs x 32 qtA
  const int hp   = x & 7;
  const int qtA  = (x >> 3) & 31;
  const int qtB  = 31 - qtA;
  const int h0   = hp * 2;
  const int kvh  = h0 >> 2;

  const int tid  = threadIdx.x;
  const int lane = tid & 63;
  const int wid  = tid >> 6;
  const int head = h0 + (wid & 1);
  const int rowbase = (wid >> 1) * 32;  // q-rows rowbase..rowbase+32 of the tile
  const int lr   = lane & 15;
  const int kg   = lane >> 4;
  const int sw   = lr & 7;

  const u16* kbase = Kc + kvh * HD;
  const u16* vbase = VT + (size_t)(kvh * HD) * S_LEN;
  u16* ps = Ps[wid];

  u16x8 kreg[4], vreg[4];
  auto stage_load = [&](int t) {
    #pragma unroll
    for (int i = 0; i < 4; ++i) {
      int c = i * 256 + tid;
      kreg[i] = *reinterpret_cast<const u16x8*>(
          kbase + (size_t)(t*64 + (c >> 4)) * KVD + (c & 15) * 8);
      vreg[i] = *reinterpret_cast<const u16x8*>(
          vbase + (size_t)(c >> 3) * S_LEN + t*64 + (c & 7) * 8);
    }
  };
  auto stage_write = [&](int b) {
    #pragma unroll
    for (int i = 0; i < 4; ++i) {
      int c = i * 256 + tid;
      int kr = c >> 4, kc = c & 15;
      *reinterpret_cast<u16x8*>(&Ks[b][kr*128 + (kc ^ (kr & 7))*8]) = kreg[i];
      int vr = c >> 3, vc = c & 7;
      *reinterpret_cast<u16x8*>(&VTs[b][vr*64 + (vc ^ (vr & 7))*8]) = vreg[i];
    }
  };

  auto run_phase = [&](int qt) {
    const int NT = qt + 1;

    bf16x8 qf[2][4];
    #pragma unroll
    for (int g = 0; g < 2; ++g) {
      const u16* qa = Q + (size_t)(qt*64 + rowbase + g*16 + lr) * E_DIM
                        + head * HD + kg * 8;
      #pragma unroll
      for (int kk = 0; kk < 4; ++kk)
        qf[g][kk] = *reinterpret_cast<const bf16x8*>(qa + kk * 32);
    }

    f32x4 o[2][8];
    #pragma unroll
    for (int g = 0; g < 2; ++g)
      #pragma unroll
      for (int d = 0; d < 8; ++d) o[g][d] = (f32x4){0.f,0.f,0.f,0.f};
    float mr[2] = {-1e30f, -1e30f}, ls[2] = {0.f, 0.f};

    stage_load(0);
    __syncthreads();   // prior phase's LDS reads all done
    stage_write(0);
    __syncthreads();

    int p = 0;
    for (int t = 0; t < NT; ++t) {
      if (t + 1 < NT) stage_load(t + 1);  // latency hides under compute

      // S^T = mfma(K, Q): K-frag read once, feeds both row-groups
      f32x4 st[2][4];
      #pragma unroll
      for (int g = 0; g < 2; ++g)
        #pragma unroll
        for (int c = 0; c < 4; ++c) st[g][c] = (f32x4){0.f,0.f,0.f,0.f};
      __builtin_amdgcn_s_setprio(1);
      #pragma unroll
      for (int kk = 0; kk < 4; ++kk) {
        #pragma unroll
        for (int c = 0; c < 4; ++c) {
          bf16x8 kfr = *reinterpret_cast<const bf16x8*>(
              &Ks[p][(c*16 + lr)*128 + ((kk*4 + kg) ^ sw)*8]);
          st[0][c] = __builtin_amdgcn_mfma_f32_16x16x32_bf16(kfr, qf[0][kk], st[0][c], 0, 0, 0);
          st[1][c] = __builtin_amdgcn_mfma_f32_16x16x32_bf16(kfr, qf[1][kk], st[1][c], 0, 0, 0);
        }
      }
      __builtin_amdgcn_s_setprio(0);

      if (t == qt) {  // causal mask, diagonal tile only
        #pragma unroll
        for (int g = 0; g < 2; ++g)
          #pragma unroll
          for (int c = 0; c < 4; ++c)
            #pragma unroll
            for (int reg = 0; reg < 4; ++reg)
              if (c*16 + kg*4 + reg > rowbase + g*16 + lr) st[g][c][reg] = -1e30f;
      }

      // softmax per row-group (independent chains -> ILP)
      #pragma unroll
      for (int g = 0; g < 2; ++g) {
        float cm[4];
        #pragma unroll
        for (int c = 0; c < 4; ++c)
          cm[c] = fmaxf(fmaxf(st[g][c][0], st[g][c][1]), fmaxf(st[g][c][2], st[g][c][3]));
        float pm = fmaxf(fmaxf(cm[0], cm[1]), fmaxf(cm[2], cm[3]));
        pm = fmaxf(pm, __shfl_xor(pm, 16));
        pm = fmaxf(pm, __shfl_xor(pm, 32));

        if (!__all(pm - mr[g] <= 8.0f)) {  // defer-max rescale (rare)
          float nm = fmaxf(mr[g], pm);
          float alpha = __expf(mr[g] - nm);
          ls[g] *= alpha;
          mr[g] = nm;
          float ar[4];
          #pragma unroll
          for (int reg = 0; reg < 4; ++reg)
            ar[reg] = __shfl(alpha, kg*4 + reg);
          #pragma unroll
          for (int d = 0; d < 8; ++d)
            #pragma unroll
            for (int reg = 0; reg < 4; ++reg)
              o[g][d][reg] *= ar[reg];
        }

        float sum = 0.f;
        #pragma unroll
        for (int c = 0; c < 4; ++c) {
          float pr[4];
          #pragma unroll
          for (int reg = 0; reg < 4; ++reg)
            pr[reg] = __expf(st[g][c][reg] - mr[g]);
          sum += (pr[0] + pr[1]) + (pr[2] + pr[3]);
          bf16x4 pk;
          #pragma unroll
          for (int reg = 0; reg < 4; ++reg) pk[reg] = (__bf16)pr[reg];
          *reinterpret_cast<bf16x4*>(&ps[(g*16 + lr)*72 + c*16 + kg*4]) = pk;
        }
        sum += __shfl_xor(sum, 16);
        sum += __shfl_xor(sum, 32);
        ls[g] += sum;
      }

      // O += P * V: V-frag read once, feeds both row-groups
      bf16x8 pa[2][2];
      #pragma unroll
      for (int g = 0; g < 2; ++g)
        #pragma unroll
        for (int kk = 0; kk < 2; ++kk)
          pa[g][kk] = *reinterpret_cast<const bf16x8*>(
              &ps[(g*16 + lr)*72 + kk*32 + kg*8]);
      __builtin_amdgcn_s_setprio(1);
      #pragma unroll
      for (int d0 = 0; d0 < 8; ++d0) {
        #pragma unroll
        for (int kk = 0; kk < 2; ++kk) {
          bf16x8 vb = *reinterpret_cast<const bf16x8*>(
              &VTs[p][(d0*16 + lr)*64 + ((kk*4 + kg) ^ sw)*8]);
          o[0][d0] = __builtin_amdgcn_mfma_f32_16x16x32_bf16(pa[0][kk], vb, o[0][d0], 0, 0, 0);
          o[1][d0] = __builtin_amdgcn_mfma_f32_16x16x32_bf16(pa[1][kk], vb, o[1][d0], 0, 0, 0);
        }
      }
      __builtin_amdgcn_s_setprio(0);

      if (t + 1 < NT) {
        stage_write(p ^ 1);  // vmcnt wait lands here, after compute
        __syncthreads();     // single barrier per tile
        p ^= 1;
      }
    }

    // epilogue per row-group
    #pragma unroll
    for (int g = 0; g < 2; ++g) {
      float inv = 1.0f / ls[g];  // valid on lane column q=lr
      float ivq[4];
      #pragma unroll
      for (int reg = 0; reg < 4; ++reg)
        ivq[reg] = __shfl(inv, kg*4 + reg);
      #pragma unroll
      for (int reg = 0; reg < 4; ++reg) {
        int grow = qt*64 + rowbase + g*16 + kg*4 + reg;
        #pragma unroll
        for (int d = 0; d < 8; ++d)
          Out[(size_t)grow * E_DIM + head * HD + d*16 + lr] =
              __builtin_bit_cast(u16, (__bf16)(o[g][d][reg] * ivq[reg]));
      }
    }
  };

  run_phase(qtA);
  run_phase(qtB);
}

// ---------------- launch ----------------
extern "C" void kernel_launch(void* const* d_in, const int* in_sizes, int n_in,
                              void* d_out, int out_size, void* d_ws, size_t ws_size,
                              hipStream_t stream)
{
  const float* x  = (const float*)d_in[0];
  const float* Wq = (const float*)d_in[1];
  const float* Wk = (const float*)d_in[2];
  const float* Wv = (const float*)d_in[3];
  const float* Wo = (const float*)d_in[4];
  const float* bo = (const float*)d_in[5];
  float* out = (float*)d_out;

  char* w = (char*)d_ws;
  u16*   xb   = (u16*)(w);                   // 8 MB  x bf16 (2048x2048)
  u16*   Wcat = (u16*)(w + (8u  << 20));     // 12 MB [Wq;Wk;Wv] bf16 (3072x2048)
  u16*   Wob  = (u16*)(w + (20u << 20));     // 8 MB  Wo bf16
  u16*   qkv  = (u16*)(w + (28u << 20));     // 12 MB qkv bf16 (2048x3072)
  u16*   qb   = (u16*)(w + (52u << 20));     // 8 MB  q bf16 roped+scaled
  u16*   kb   = (u16*)(w + (60u << 20));     // 2 MB  k bf16 roped
  u16*   vT   = (u16*)(w + (62u << 20));     // 2 MB  v^T bf16 (512x2048)
  u16*   attn = (u16*)(w + (64u << 20));     // 8 MB  attention out bf16
  (void)ws_size; (void)in_sizes; (void)n_in; (void)out_size;

  cast_all_kernel<<<14336, 256, 0, stream>>>(x, Wq, Wk, Wv, Wo, xb, Wcat, Wob);

  gemm_bt_kernel<false, true><<<dim3(NQKV/128, S_LEN/128), 512, 0, stream>>>(
      xb, Wcat, qkv, nullptr, S_LEN, NQKV, E_DIM);

  rope_split_kernel<<<(S_LEN * 1280) / 256, 256, 0, stream>>>(qkv, qb, kb);
  transpose_v_kernel<<<dim3(S_LEN/32, KVD/32), dim3(32, 8), 0, stream>>>(qkv, vT);

  attn_kernel<<<256, 256, 0, stream>>>(qb, kb, vT, attn);

  gemm_bt_kernel<true, false><<<dim3(E_DIM/128, S_LEN/128), 512, 0, stream>>>(
      attn, Wob, out, bo, S_LEN, E_DIM, E_DIM);
}

// Round 12
// 137.520 us; speedup vs baseline: 1.2613x; 1.2613x over previous
//
#include <hip/hip_runtime.h>
#include <stdint.h>

typedef unsigned short u16;
typedef float  f32x4  __attribute__((ext_vector_type(4)));
typedef __bf16 bf16x8 __attribute__((ext_vector_type(8)));
typedef __bf16 bf16x4 __attribute__((ext_vector_type(4)));
typedef unsigned short u16x8 __attribute__((ext_vector_type(8)));
typedef unsigned short u16x4v __attribute__((ext_vector_type(4)));

#define S_LEN 2048
#define E_DIM 2048
#define HD    128
#define QH    16
#define KVH   4
#define KVD   512
#define NQKV  3072
#define QK_SCALE 0.08838834764831845f  // 1/sqrt(128)

#define AS1 __attribute__((address_space(1)))
#define AS3 __attribute__((address_space(3)))

__device__ __forceinline__ u16 f2bf(float f) {
  union { float f; uint32_t u; } v; v.f = f;
  return (u16)((v.u + 0x7FFFu + ((v.u >> 16) & 1u)) >> 16);
}

// ---------------- fused cast fp32->bf16 (5 tensors) + RoPE trig table ----------
// quads: x 1M | Wq 1M | Wk 256K | Wv 256K | Wo 1M = 3670016 (14336 blocks);
// then 131072 table entries (512 blocks): tab[s*64+p] = {cos(s*w_p), sin(s*w_p)}
__global__ void cast_all_kernel(const float* __restrict__ x, const float* __restrict__ Wq,
                                const float* __restrict__ Wk, const float* __restrict__ Wv,
                                const float* __restrict__ Wo,
                                u16* __restrict__ xb, u16* __restrict__ Wcat,
                                u16* __restrict__ Wob, float2* __restrict__ tab) {
  int i = blockIdx.x * blockDim.x + threadIdx.x;
  if (i >= 3670016) {           // rope table
    int j = i - 3670016;        // 0 .. 131071
    int s = j >> 6, pidx = j & 63;
    float inv = exp2f((float)pidx * (-13.287712379549449f / 64.0f));  // 10000^(-p/64)
    float sn, cs;
    sincosf((float)s * inv, &sn, &cs);
    tab[j] = make_float2(cs, sn);
    return;
  }
  const float* src; u16* dst;
  if (i < (1 << 20))                       { src = x  + (size_t)i * 4;  dst = xb + (size_t)i * 4; }
  else if (i < (2 << 20))                  { size_t j = i - (1 << 20);  src = Wq + j * 4; dst = Wcat + j * 4; }
  else if (i < (2 << 20) + (1 << 18))      { size_t j = i - (2 << 20);  src = Wk + j * 4; dst = Wcat + (size_t)E_DIM * E_DIM + j * 4; }
  else if (i < (2 << 20) + (2 << 18))      { size_t j = i - (2 << 20) - (1 << 18); src = Wv + j * 4; dst = Wcat + (size_t)(E_DIM + KVD) * E_DIM + j * 4; }
  else                                     { size_t j = i - (2 << 20) - (2 << 18); src = Wo + j * 4; dst = Wob + j * 4; }
  float4 f = *reinterpret_cast<const float4*>(src);
  u16x4v o;
  o[0] = f2bf(f.x); o[1] = f2bf(f.y); o[2] = f2bf(f.z); o[3] = f2bf(f.w);
  *reinterpret_cast<u16x4v*>(dst) = o;
}

// ---------------- GEMM: C[M,N] = A[M,K] * B[N,K]^T, bf16 in -------------------
// 128x128 tile, BK=64, 512 threads = 8 waves (2x4, each owns 64x32).
// 2-phase dbuf, global_load_lds w16 for t+1 issued before compute of t,
// source-side XOR swizzle -> conflict-free b128 reads.
// MODE 0: fp32 C + bias (out-proj).  MODE 2: fused QKV epilogue -- RoPE
// (pair exchange via shfl_xor(.,1), trig from tab) -> qb (scaled) / kb bf16,
// V written TRANSPOSED to vT as 8B bf16x4 stores. Region is block-uniform.
template<bool BIAS, int MODE>
__global__ __launch_bounds__(512) void gemm_bt_kernel(
    const u16* __restrict__ A, const u16* __restrict__ B,
    float* __restrict__ C, const float* __restrict__ bias,
    const float2* __restrict__ tab, u16* __restrict__ qb,
    u16* __restrict__ kb, u16* __restrict__ vTp,
    int M, int N, int K)
{
  __shared__ u16 As[2][128 * 64];
  __shared__ u16 Bs[2][128 * 64];

  const int tid  = threadIdx.x;
  const int lane = tid & 63;
  const int wid  = tid >> 6;           // 0..7
  const int wr   = (wid >> 2) * 64;    // 2 wave-rows
  const int wc   = (wid & 3) * 32;     // 4 wave-cols
  const int lr   = lane & 15;
  const int kg   = lane >> 4;
  const int sw   = lr & 7;

  const int bm = blockIdx.y * 128;
  const int bn = blockIdx.x * 128;

  f32x4 acc[4][2];
  #pragma unroll
  for (int r = 0; r < 4; ++r)
    #pragma unroll
    for (int c = 0; c < 2; ++c) acc[r][c] = (f32x4){0.f, 0.f, 0.f, 0.f};

  const int srow   = wid * 8 + (lane >> 3);
  const int schunk = (lane & 7) ^ (lane >> 3);

  const u16* gA = A + (size_t)(bm + srow) * K + schunk * 8;
  const u16* gB = B + (size_t)(bn + srow) * K + schunk * 8;

  auto stage = [&](int buf, int kt) {
    #pragma unroll
    for (int i = 0; i < 2; ++i) {
      __builtin_amdgcn_global_load_lds(
          (const AS1 void*)(gA + (size_t)i * 64 * K + kt),
          (AS3 void*)(&As[buf][(wid*8 + i*64) * 64]), 16, 0, 0);
      __builtin_amdgcn_global_load_lds(
          (const AS1 void*)(gB + (size_t)i * 64 * K + kt),
          (AS3 void*)(&Bs[buf][(wid*8 + i*64) * 64]), 16, 0, 0);
    }
  };

  stage(0, 0);
  __syncthreads();

  int cur = 0;
  for (int kt = 0; kt < K; kt += 64) {
    if (kt + 64 < K) stage(cur ^ 1, kt + 64);
    #pragma unroll
    for (int kk = 0; kk < 2; ++kk) {
      bf16x8 af[4], bfr[2];
      #pragma unroll
      for (int r = 0; r < 4; ++r)
        af[r] = *reinterpret_cast<const bf16x8*>(
            &As[cur][(wr + r*16 + lr)*64 + ((kk*4 + kg) ^ sw)*8]);
      #pragma unroll
      for (int c = 0; c < 2; ++c)
        bfr[c] = *reinterpret_cast<const bf16x8*>(
            &Bs[cur][(wc + c*16 + lr)*64 + ((kk*4 + kg) ^ sw)*8]);
      #pragma unroll
      for (int r = 0; r < 4; ++r)
        #pragma unroll
        for (int c = 0; c < 2; ++c)
          acc[r][c] = __builtin_amdgcn_mfma_f32_16x16x32_bf16(af[r], bfr[c], acc[r][c], 0, 0, 0);
    }
    __syncthreads();
    cur ^= 1;
  }

  const int crow = kg * 4;
  #pragma unroll
  for (int r = 0; r < 4; ++r) {
    #pragma unroll
    for (int c = 0; c < 2; ++c) {
      int gr = bm + wr + r*16 + crow;
      int gc = bn + wc + c*16 + lr;
      if constexpr (MODE == 0) {
        float badd = BIAS ? bias[gc] : 0.0f;
        #pragma unroll
        for (int reg = 0; reg < 4; ++reg)
          C[(size_t)(gr + reg)*N + gc] = acc[r][c][reg] + badd;
      } else {  // MODE 2: fused QKV epilogue
        if (gc < E_DIM + KVD) {
          // RoPE: pair (even,odd col) lives on lanes (lr, lr^1), same wave.
          int pidx = (gc & 127) >> 1;
          bool odd = lr & 1;
          #pragma unroll
          for (int reg = 0; reg < 4; ++reg) {
            float val = acc[r][c][reg];
            float oth = __shfl_xor(val, 1);
            float2 cs = tab[(gr + reg) * 64 + pidx];
            float o = odd ? (oth * cs.y + val * cs.x)
                          : (val * cs.x - oth * cs.y);
            if (gc < E_DIM)
              qb[(size_t)(gr + reg) * E_DIM + gc] = f2bf(o * QK_SCALE);
            else
              kb[(size_t)(gr + reg) * KVD + (gc - E_DIM)] = f2bf(o);
          }
        } else {
          // V: write transposed, 4 consecutive rows -> one 8B store
          bf16x4 pk;
          #pragma unroll
          for (int reg = 0; reg < 4; ++reg) pk[reg] = (__bf16)acc[r][c][reg];
          *reinterpret_cast<bf16x4*>(
              &vTp[(size_t)(gc - E_DIM - KVD) * S_LEN + gr]) = pk;
        }
      }
    }
  }
}

// ---------------- Flash attention tile, SWAPPED QK^T (r4/r10-proven) -----------
__device__ __forceinline__ void attn_tile(
    int t, int qt, int wid, int lr, int kg,
    const bf16x8* qf, f32x4* o, float& mr, float& ls,
    const u16* ks, const u16* vts, u16* ps)
{
  const int sw = lr & 7;
  f32x4 st[4];
  #pragma unroll
  for (int c = 0; c < 4; ++c) st[c] = (f32x4){0.f, 0.f, 0.f, 0.f};
  __builtin_amdgcn_s_setprio(1);
  #pragma unroll
  for (int kk = 0; kk < 4; ++kk) {
    #pragma unroll
    for (int c = 0; c < 4; ++c) {
      bf16x8 kfr = *reinterpret_cast<const bf16x8*>(
          &ks[(c*16 + lr)*128 + ((kk*4 + kg) ^ sw)*8]);
      st[c] = __builtin_amdgcn_mfma_f32_16x16x32_bf16(kfr, qf[kk], st[c], 0, 0, 0);
    }
  }
  __builtin_amdgcn_s_setprio(0);
  if (t == qt) {  // causal: mask kv > q (local coords)
    #pragma unroll
    for (int c = 0; c < 4; ++c)
      #pragma unroll
      for (int reg = 0; reg < 4; ++reg)
        if (c*16 + kg*4 + reg > wid*16 + lr) st[c][reg] = -1e30f;
  }
  float cm[4];
  #pragma unroll
  for (int c = 0; c < 4; ++c)
    cm[c] = fmaxf(fmaxf(st[c][0], st[c][1]), fmaxf(st[c][2], st[c][3]));
  float pm = fmaxf(fmaxf(cm[0], cm[1]), fmaxf(cm[2], cm[3]));
  pm = fmaxf(pm, __shfl_xor(pm, 16));
  pm = fmaxf(pm, __shfl_xor(pm, 32));

  if (!__all(pm - mr <= 8.0f)) {  // defer-max: rare after first tile
    float nm = fmaxf(mr, pm);
    float alpha = __expf(mr - nm);
    ls *= alpha;
    mr = nm;
    float ar[4];
    #pragma unroll
    for (int reg = 0; reg < 4; ++reg)
      ar[reg] = __shfl(alpha, kg*4 + reg);
    #pragma unroll
    for (int d = 0; d < 8; ++d)
      #pragma unroll
      for (int reg = 0; reg < 4; ++reg)
        o[d][reg] *= ar[reg];
  }

  float p[4][4];
  float csum[4];
  #pragma unroll
  for (int c = 0; c < 4; ++c) {
    #pragma unroll
    for (int reg = 0; reg < 4; ++reg)
      p[c][reg] = __expf(st[c][reg] - mr);
    csum[c] = (p[c][0] + p[c][1]) + (p[c][2] + p[c][3]);
  }
  float sum = (csum[0] + csum[1]) + (csum[2] + csum[3]);
  sum += __shfl_xor(sum, 16);
  sum += __shfl_xor(sum, 32);
  ls += sum;

  #pragma unroll
  for (int c = 0; c < 4; ++c) {
    bf16x4 pk;
    #pragma unroll
    for (int reg = 0; reg < 4; ++reg) pk[reg] = (__bf16)p[c][reg];
    *reinterpret_cast<bf16x4*>(&ps[lr*72 + c*16 + kg*4]) = pk;
  }
  __builtin_amdgcn_s_setprio(1);
  #pragma unroll
  for (int kk = 0; kk < 2; ++kk) {
    bf16x8 pa = *reinterpret_cast<const bf16x8*>(&ps[lr*72 + kk*32 + kg*8]);
    #pragma unroll
    for (int d = 0; d < 8; ++d) {
      bf16x8 vb = *reinterpret_cast<const bf16x8*>(
          &vts[(d*16 + lr)*64 + ((kk*4 + kg) ^ sw)*8]);
      o[d] = __builtin_amdgcn_mfma_f32_16x16x32_bf16(pa, vb, o[d], 0, 0, 0);
    }
  }
  __builtin_amdgcn_s_setprio(0);
}

// ---------------- Flash attention (causal, GQA 4:1) -- r4/r10-proven config ----
__global__ __launch_bounds__(256, 2) void attn_kernel(
    const u16* __restrict__ Q, const u16* __restrict__ Kc,
    const u16* __restrict__ VT, u16* __restrict__ Out)
{
  __shared__ u16 Ks[2][64 * 128];
  __shared__ u16 VTs[2][128 * 64];
  __shared__ u16 Ps[4][16 * 72];

  const int x = blockIdx.x;
  int qt, h;
  if (x < 256) { qt = x & 31; h = x >> 5; }
  else         { int xp = x - 256; qt = 31 - (xp & 31); h = 8 + (xp >> 5); }
  const int kvh = h >> 2;
  const int tid  = threadIdx.x;
  const int lane = tid & 63;
  const int wid  = tid >> 6;
  const int lr   = lane & 15;
  const int kg   = lane >> 4;

  const int NT = qt + 1;

  bf16x8 qf[4];
  {
    const u16* qa = Q + (size_t)(qt*64 + wid*16 + lr) * E_DIM + h * HD + kg * 8;
    #pragma unroll
    for (int kk = 0; kk < 4; ++kk)
      qf[kk] = *reinterpret_cast<const bf16x8*>(qa + kk * 32);
  }

  f32x4 o[8];
  #pragma unroll
  for (int d = 0; d < 8; ++d) o[d] = (f32x4){0.f,0.f,0.f,0.f};
  float mr = -1e30f, ls = 0.f;

  u16x8 kreg[4], vreg[4];
  const u16* kbase = Kc + kvh * HD;
  const u16* vbase = VT + (size_t)(kvh * HD) * S_LEN;

  auto stage_load = [&](int t) {
    #pragma unroll
    for (int i = 0; i < 4; ++i) {
      int c = i * 256 + tid;
      kreg[i] = *reinterpret_cast<const u16x8*>(
          kbase + (size_t)(t*64 + (c >> 4)) * KVD + (c & 15) * 8);
      vreg[i] = *reinterpret_cast<const u16x8*>(
          vbase + (size_t)(c >> 3) * S_LEN + t*64 + (c & 7) * 8);
    }
  };
  auto stage_write = [&](int b) {
    #pragma unroll
    for (int i = 0; i < 4; ++i) {
      int c = i * 256 + tid;
      int kr = c >> 4, kc = c & 15;
      *reinterpret_cast<u16x8*>(&Ks[b][kr*128 + (kc ^ (kr & 7))*8]) = kreg[i];
      int vr = c >> 3, vc = c & 7;
      *reinterpret_cast<u16x8*>(&VTs[b][vr*64 + (vc ^ (vr & 7))*8]) = vreg[i];
    }
  };

  int p = 0;
  stage_load(0);
  stage_write(0);
  __syncthreads();

  for (int t = 0; t < NT; ++t) {
    if (t + 1 < NT) stage_load(t + 1);  // issue early: latency hides under MFMAs
    attn_tile(t, qt, wid, lr, kg, qf, o, mr, ls, Ks[p], VTs[p], Ps[wid]);
    if (t + 1 < NT) {
      stage_write(p ^ 1);  // vmcnt wait lands here, after compute
      __syncthreads();     // single barrier per tile
      p ^= 1;
    }
  }

  {
    float inv = 1.0f / ls;  // for q = lr
    float ivq[4];
    #pragma unroll
    for (int reg = 0; reg < 4; ++reg)
      ivq[reg] = __shfl(inv, kg*4 + reg);
    #pragma unroll
    for (int reg = 0; reg < 4; ++reg) {
      int grow = qt*64 + wid*16 + kg*4 + reg;
      #pragma unroll
      for (int d = 0; d < 8; ++d)
        Out[(size_t)grow * E_DIM + h * HD + d*16 + lr] =
            __builtin_bit_cast(u16, (__bf16)(o[d][reg] * ivq[reg]));
    }
  }
}

// ---------------- launch ----------------
extern "C" void kernel_launch(void* const* d_in, const int* in_sizes, int n_in,
                              void* d_out, int out_size, void* d_ws, size_t ws_size,
                              hipStream_t stream)
{
  const float* x  = (const float*)d_in[0];
  const float* Wq = (const float*)d_in[1];
  const float* Wk = (const float*)d_in[2];
  const float* Wv = (const float*)d_in[3];
  const float* Wo = (const float*)d_in[4];
  const float* bo = (const float*)d_in[5];
  float* out = (float*)d_out;

  char* w = (char*)d_ws;
  u16*    xb   = (u16*)(w);                   // 8 MB  x bf16 (2048x2048)
  u16*    Wcat = (u16*)(w + (8u  << 20));     // 12 MB [Wq;Wk;Wv] bf16 (3072x2048)
  u16*    Wob  = (u16*)(w + (20u << 20));     // 8 MB  Wo bf16
  float2* tab  = (float2*)(w + (28u << 20));  // 1 MB  rope table (2048x64)
  u16*    qb   = (u16*)(w + (30u << 20));     // 8 MB  q bf16 roped+scaled
  u16*    kb   = (u16*)(w + (38u << 20));     // 2 MB  k bf16 roped
  u16*    vT   = (u16*)(w + (40u << 20));     // 2 MB  v^T bf16 (512x2048)
  u16*    attn = (u16*)(w + (42u << 20));     // 8 MB  attention out bf16
  (void)ws_size; (void)in_sizes; (void)n_in; (void)out_size;

  cast_all_kernel<<<14848, 256, 0, stream>>>(x, Wq, Wk, Wv, Wo, xb, Wcat, Wob, tab);

  gemm_bt_kernel<false, 2><<<dim3(NQKV/128, S_LEN/128), 512, 0, stream>>>(
      xb, Wcat, nullptr, nullptr, tab, qb, kb, vT, S_LEN, NQKV, E_DIM);

  attn_kernel<<<512, 256, 0, stream>>>(qb, kb, vT, attn);

  gemm_bt_kernel<true, 0><<<dim3(E_DIM/128, S_LEN/128), 512, 0, stream>>>(
      attn, Wob, out, bo, nullptr, nullptr, nullptr, nullptr, S_LEN, E_DIM, E_DIM);
}

// Round 13
// 133.797 us; speedup vs baseline: 1.2964x; 1.0278x over previous
//
#include <hip/hip_runtime.h>
#include <stdint.h>

typedef unsigned short u16;
typedef float  f32x4  __attribute__((ext_vector_type(4)));
typedef __bf16 bf16x8 __attribute__((ext_vector_type(8)));
typedef __bf16 bf16x4 __attribute__((ext_vector_type(4)));
typedef unsigned short u16x8 __attribute__((ext_vector_type(8)));
typedef unsigned short u16x4v __attribute__((ext_vector_type(4)));

#define S_LEN 2048
#define E_DIM 2048
#define HD    128
#define QH    16
#define KVH   4
#define KVD   512
#define NQKV  3072
#define QK_SCALE 0.08838834764831845f  // 1/sqrt(128)

#define AS1 __attribute__((address_space(1)))
#define AS3 __attribute__((address_space(3)))

__device__ __forceinline__ u16 f2bf(float f) {
  union { float f; uint32_t u; } v; v.f = f;
  return (u16)((v.u + 0x7FFFu + ((v.u >> 16) & 1u)) >> 16);
}

// ---------------- fused cast fp32->bf16 (5 tensors) + RoPE trig table ----------
__global__ void cast_all_kernel(const float* __restrict__ x, const float* __restrict__ Wq,
                                const float* __restrict__ Wk, const float* __restrict__ Wv,
                                const float* __restrict__ Wo,
                                u16* __restrict__ xb, u16* __restrict__ Wcat,
                                u16* __restrict__ Wob, float2* __restrict__ tab) {
  int i = blockIdx.x * blockDim.x + threadIdx.x;
  if (i >= 3670016) {           // rope table
    int j = i - 3670016;        // 0 .. 131071
    int s = j >> 6, pidx = j & 63;
    float inv = exp2f((float)pidx * (-13.287712379549449f / 64.0f));  // 10000^(-p/64)
    float sn, cs;
    sincosf((float)s * inv, &sn, &cs);
    tab[j] = make_float2(cs, sn);
    return;
  }
  const float* src; u16* dst;
  if (i < (1 << 20))                       { src = x  + (size_t)i * 4;  dst = xb + (size_t)i * 4; }
  else if (i < (2 << 20))                  { size_t j = i - (1 << 20);  src = Wq + j * 4; dst = Wcat + j * 4; }
  else if (i < (2 << 20) + (1 << 18))      { size_t j = i - (2 << 20);  src = Wk + j * 4; dst = Wcat + (size_t)E_DIM * E_DIM + j * 4; }
  else if (i < (2 << 20) + (2 << 18))      { size_t j = i - (2 << 20) - (1 << 18); src = Wv + j * 4; dst = Wcat + (size_t)(E_DIM + KVD) * E_DIM + j * 4; }
  else                                     { size_t j = i - (2 << 20) - (2 << 18); src = Wo + j * 4; dst = Wob + j * 4; }
  float4 f = *reinterpret_cast<const float4*>(src);
  u16x4v o;
  o[0] = f2bf(f.x); o[1] = f2bf(f.y); o[2] = f2bf(f.z); o[3] = f2bf(f.w);
  *reinterpret_cast<u16x4v*>(dst) = o;
}

// ---------------- GEMM: C[M,N] = A[M,K] * B[N,K]^T, bf16 in -------------------
// 64x128 tile (M x N), BK=64, 256 threads = 4 waves (1x4, each owns 64x32).
// Grid: QKV 32x24=768 blocks (3/CU exact), out-proj 32x16=512 (2/CU exact) --
// no tail rounds; 48 KB LDS -> 2 blocks co-resident, inter-block overlap.
// 2-phase dbuf, global_load_lds w16 for t+1 issued before compute of t,
// source-side XOR swizzle -> conflict-free b128 reads.
// MODE 0: fp32 C + bias.  MODE 2: fused QKV epilogue (RoPE via shfl_xor pair
// exchange + trig table -> qb/kb; V written transposed to vT).
template<bool BIAS, int MODE>
__global__ __launch_bounds__(256) void gemm_bt_kernel(
    const u16* __restrict__ A, const u16* __restrict__ B,
    float* __restrict__ C, const float* __restrict__ bias,
    const float2* __restrict__ tab, u16* __restrict__ qb,
    u16* __restrict__ kb, u16* __restrict__ vTp,
    int M, int N, int K)
{
  __shared__ u16 As[2][64 * 64];    // 8 KB x2
  __shared__ u16 Bs[2][128 * 64];   // 16 KB x2

  const int tid  = threadIdx.x;
  const int lane = tid & 63;
  const int wid  = tid >> 6;        // 0..3
  const int wc   = wid * 32;        // wave column base (rows: all 64)
  const int lr   = lane & 15;
  const int kg   = lane >> 4;
  const int sw   = lr & 7;

  const int bm = blockIdx.y * 64;
  const int bn = blockIdx.x * 128;

  f32x4 acc[4][2];
  #pragma unroll
  for (int r = 0; r < 4; ++r)
    #pragma unroll
    for (int c = 0; c < 2; ++c) acc[r][c] = (f32x4){0.f, 0.f, 0.f, 0.f};

  // staging: issue covers 32 rows (4 waves x 8); lane l -> row +(l>>3),
  // LDS slot l&7; source chunk = (l&7)^(l>>3) == slot^(row&7).
  const int srow   = wid * 8 + (lane >> 3);
  const int schunk = (lane & 7) ^ (lane >> 3);

  const u16* gA = A + (size_t)(bm + srow) * K + schunk * 8;
  const u16* gB = B + (size_t)(bn + srow) * K + schunk * 8;

  auto stage = [&](int buf, int kt) {
    #pragma unroll
    for (int i = 0; i < 2; ++i)
      __builtin_amdgcn_global_load_lds(
          (const AS1 void*)(gA + (size_t)i * 32 * K + kt),
          (AS3 void*)(&As[buf][(wid*8 + i*32) * 64]), 16, 0, 0);
    #pragma unroll
    for (int i = 0; i < 4; ++i)
      __builtin_amdgcn_global_load_lds(
          (const AS1 void*)(gB + (size_t)i * 32 * K + kt),
          (AS3 void*)(&Bs[buf][(wid*8 + i*32) * 64]), 16, 0, 0);
  };

  stage(0, 0);
  __syncthreads();

  int cur = 0;
  for (int kt = 0; kt < K; kt += 64) {
    if (kt + 64 < K) stage(cur ^ 1, kt + 64);  // in flight across the MFMAs
    #pragma unroll
    for (int kk = 0; kk < 2; ++kk) {
      bf16x8 af[4], bfr[2];
      #pragma unroll
      for (int r = 0; r < 4; ++r)
        af[r] = *reinterpret_cast<const bf16x8*>(
            &As[cur][(r*16 + lr)*64 + ((kk*4 + kg) ^ sw)*8]);
      #pragma unroll
      for (int c = 0; c < 2; ++c)
        bfr[c] = *reinterpret_cast<const bf16x8*>(
            &Bs[cur][(wc + c*16 + lr)*64 + ((kk*4 + kg) ^ sw)*8]);
      #pragma unroll
      for (int r = 0; r < 4; ++r)
        #pragma unroll
        for (int c = 0; c < 2; ++c)
          acc[r][c] = __builtin_amdgcn_mfma_f32_16x16x32_bf16(af[r], bfr[c], acc[r][c], 0, 0, 0);
    }
    __syncthreads();
    cur ^= 1;
  }

  const int crow = kg * 4;
  #pragma unroll
  for (int r = 0; r < 4; ++r) {
    #pragma unroll
    for (int c = 0; c < 2; ++c) {
      int gr = bm + r*16 + crow;
      int gc = bn + wc + c*16 + lr;
      if constexpr (MODE == 0) {
        float badd = BIAS ? bias[gc] : 0.0f;
        #pragma unroll
        for (int reg = 0; reg < 4; ++reg)
          C[(size_t)(gr + reg)*N + gc] = acc[r][c][reg] + badd;
      } else {  // MODE 2: fused QKV epilogue
        if (gc < E_DIM + KVD) {
          // RoPE: pair (even,odd col) lives on lanes (lr, lr^1), same wave.
          int pidx = (gc & 127) >> 1;
          bool odd = lr & 1;
          #pragma unroll
          for (int reg = 0; reg < 4; ++reg) {
            float val = acc[r][c][reg];
            float oth = __shfl_xor(val, 1);
            float2 cs = tab[(gr + reg) * 64 + pidx];
            float o = odd ? (oth * cs.y + val * cs.x)
                          : (val * cs.x - oth * cs.y);
            if (gc < E_DIM)
              qb[(size_t)(gr + reg) * E_DIM + gc] = f2bf(o * QK_SCALE);
            else
              kb[(size_t)(gr + reg) * KVD + (gc - E_DIM)] = f2bf(o);
          }
        } else {
          // V: write transposed, 4 consecutive rows -> one 8B store
          bf16x4 pk;
          #pragma unroll
          for (int reg = 0; reg < 4; ++reg) pk[reg] = (__bf16)acc[r][c][reg];
          *reinterpret_cast<bf16x4*>(
              &vTp[(size_t)(gc - E_DIM - KVD) * S_LEN + gr]) = pk;
        }
      }
    }
  }
}

// ---------------- Flash attention tile, SWAPPED QK^T (r4/r10-proven) -----------
__device__ __forceinline__ void attn_tile(
    int t, int qt, int wid, int lr, int kg,
    const bf16x8* qf, f32x4* o, float& mr, float& ls,
    const u16* ks, const u16* vts, u16* ps)
{
  const int sw = lr & 7;
  f32x4 st[4];
  #pragma unroll
  for (int c = 0; c < 4; ++c) st[c] = (f32x4){0.f, 0.f, 0.f, 0.f};
  __builtin_amdgcn_s_setprio(1);
  #pragma unroll
  for (int kk = 0; kk < 4; ++kk) {
    #pragma unroll
    for (int c = 0; c < 4; ++c) {
      bf16x8 kfr = *reinterpret_cast<const bf16x8*>(
          &ks[(c*16 + lr)*128 + ((kk*4 + kg) ^ sw)*8]);
      st[c] = __builtin_amdgcn_mfma_f32_16x16x32_bf16(kfr, qf[kk], st[c], 0, 0, 0);
    }
  }
  __builtin_amdgcn_s_setprio(0);
  if (t == qt) {  // causal: mask kv > q (local coords)
    #pragma unroll
    for (int c = 0; c < 4; ++c)
      #pragma unroll
      for (int reg = 0; reg < 4; ++reg)
        if (c*16 + kg*4 + reg > wid*16 + lr) st[c][reg] = -1e30f;
  }
  float cm[4];
  #pragma unroll
  for (int c = 0; c < 4; ++c)
    cm[c] = fmaxf(fmaxf(st[c][0], st[c][1]), fmaxf(st[c][2], st[c][3]));
  float pm = fmaxf(fmaxf(cm[0], cm[1]), fmaxf(cm[2], cm[3]));
  pm = fmaxf(pm, __shfl_xor(pm, 16));
  pm = fmaxf(pm, __shfl_xor(pm, 32));

  if (!__all(pm - mr <= 8.0f)) {  // defer-max: rare after first tile
    float nm = fmaxf(mr, pm);
    float alpha = __expf(mr - nm);
    ls *= alpha;
    mr = nm;
    float ar[4];
    #pragma unroll
    for (int reg = 0; reg < 4; ++reg)
      ar[reg] = __shfl(alpha, kg*4 + reg);
    #pragma unroll
    for (int d = 0; d < 8; ++d)
      #pragma unroll
      for (int reg = 0; reg < 4; ++reg)
        o[d][reg] *= ar[reg];
  }

  float p[4][4];
  float csum[4];
  #pragma unroll
  for (int c = 0; c < 4; ++c) {
    #pragma unroll
    for (int reg = 0; reg < 4; ++reg)
      p[c][reg] = __expf(st[c][reg] - mr);
    csum[c] = (p[c][0] + p[c][1]) + (p[c][2] + p[c][3]);
  }
  float sum = (csum[0] + csum[1]) + (csum[2] + csum[3]);
  sum += __shfl_xor(sum, 16);
  sum += __shfl_xor(sum, 32);
  ls += sum;

  #pragma unroll
  for (int c = 0; c < 4; ++c) {
    bf16x4 pk;
    #pragma unroll
    for (int reg = 0; reg < 4; ++reg) pk[reg] = (__bf16)p[c][reg];
    *reinterpret_cast<bf16x4*>(&ps[lr*72 + c*16 + kg*4]) = pk;
  }
  __builtin_amdgcn_s_setprio(1);
  #pragma unroll
  for (int kk = 0; kk < 2; ++kk) {
    bf16x8 pa = *reinterpret_cast<const bf16x8*>(&ps[lr*72 + kk*32 + kg*8]);
    #pragma unroll
    for (int d = 0; d < 8; ++d) {
      bf16x8 vb = *reinterpret_cast<const bf16x8*>(
          &vts[(d*16 + lr)*64 + ((kk*4 + kg) ^ sw)*8]);
      o[d] = __builtin_amdgcn_mfma_f32_16x16x32_bf16(pa, vb, o[d], 0, 0, 0);
    }
  }
  __builtin_amdgcn_s_setprio(0);
}

// ---------------- Flash attention (causal, GQA 4:1) -- r4/r10-proven config ----
__global__ __launch_bounds__(256, 2) void attn_kernel(
    const u16* __restrict__ Q, const u16* __restrict__ Kc,
    const u16* __restrict__ VT, u16* __restrict__ Out)
{
  __shared__ u16 Ks[2][64 * 128];
  __shared__ u16 VTs[2][128 * 64];
  __shared__ u16 Ps[4][16 * 72];

  const int x = blockIdx.x;
  int qt, h;
  if (x < 256) { qt = x & 31; h = x >> 5; }
  else         { int xp = x - 256; qt = 31 - (xp & 31); h = 8 + (xp >> 5); }
  const int kvh = h >> 2;
  const int tid  = threadIdx.x;
  const int lane = tid & 63;
  const int wid  = tid >> 6;
  const int lr   = lane & 15;
  const int kg   = lane >> 4;

  const int NT = qt + 1;

  bf16x8 qf[4];
  {
    const u16* qa = Q + (size_t)(qt*64 + wid*16 + lr) * E_DIM + h * HD + kg * 8;
    #pragma unroll
    for (int kk = 0; kk < 4; ++kk)
      qf[kk] = *reinterpret_cast<const bf16x8*>(qa + kk * 32);
  }

  f32x4 o[8];
  #pragma unroll
  for (int d = 0; d < 8; ++d) o[d] = (f32x4){0.f,0.f,0.f,0.f};
  float mr = -1e30f, ls = 0.f;

  u16x8 kreg[4], vreg[4];
  const u16* kbase = Kc + kvh * HD;
  const u16* vbase = VT + (size_t)(kvh * HD) * S_LEN;

  auto stage_load = [&](int t) {
    #pragma unroll
    for (int i = 0; i < 4; ++i) {
      int c = i * 256 + tid;
      kreg[i] = *reinterpret_cast<const u16x8*>(
          kbase + (size_t)(t*64 + (c >> 4)) * KVD + (c & 15) * 8);
      vreg[i] = *reinterpret_cast<const u16x8*>(
          vbase + (size_t)(c >> 3) * S_LEN + t*64 + (c & 7) * 8);
    }
  };
  auto stage_write = [&](int b) {
    #pragma unroll
    for (int i = 0; i < 4; ++i) {
      int c = i * 256 + tid;
      int kr = c >> 4, kc = c & 15;
      *reinterpret_cast<u16x8*>(&Ks[b][kr*128 + (kc ^ (kr & 7))*8]) = kreg[i];
      int vr = c >> 3, vc = c & 7;
      *reinterpret_cast<u16x8*>(&VTs[b][vr*64 + (vc ^ (vr & 7))*8]) = vreg[i];
    }
  };

  int p = 0;
  stage_load(0);
  stage_write(0);
  __syncthreads();

  for (int t = 0; t < NT; ++t) {
    if (t + 1 < NT) stage_load(t + 1);  // issue early: latency hides under MFMAs
    attn_tile(t, qt, wid, lr, kg, qf, o, mr, ls, Ks[p], VTs[p], Ps[wid]);
    if (t + 1 < NT) {
      stage_write(p ^ 1);  // vmcnt wait lands here, after compute
      __syncthreads();     // single barrier per tile
      p ^= 1;
    }
  }

  {
    float inv = 1.0f / ls;  // for q = lr
    float ivq[4];
    #pragma unroll
    for (int reg = 0; reg < 4; ++reg)
      ivq[reg] = __shfl(inv, kg*4 + reg);
    #pragma unroll
    for (int reg = 0; reg < 4; ++reg) {
      int grow = qt*64 + wid*16 + kg*4 + reg;
      #pragma unroll
      for (int d = 0; d < 8; ++d)
        Out[(size_t)grow * E_DIM + h * HD + d*16 + lr] =
            __builtin_bit_cast(u16, (__bf16)(o[d][reg] * ivq[reg]));
    }
  }
}

// ---------------- launch ----------------
extern "C" void kernel_launch(void* const* d_in, const int* in_sizes, int n_in,
                              void* d_out, int out_size, void* d_ws, size_t ws_size,
                              hipStream_t stream)
{
  const float* x  = (const float*)d_in[0];
  const float* Wq = (const float*)d_in[1];
  const float* Wk = (const float*)d_in[2];
  const float* Wv = (const float*)d_in[3];
  const float* Wo = (const float*)d_in[4];
  const float* bo = (const float*)d_in[5];
  float* out = (float*)d_out;

  char* w = (char*)d_ws;
  u16*    xb   = (u16*)(w);                   // 8 MB  x bf16 (2048x2048)
  u16*    Wcat = (u16*)(w + (8u  << 20));     // 12 MB [Wq;Wk;Wv] bf16 (3072x2048)
  u16*    Wob  = (u16*)(w + (20u << 20));     // 8 MB  Wo bf16
  float2* tab  = (float2*)(w + (28u << 20));  // 1 MB  rope table (2048x64)
  u16*    qb   = (u16*)(w + (30u << 20));     // 8 MB  q bf16 roped+scaled
  u16*    kb   = (u16*)(w + (38u << 20));     // 2 MB  k bf16 roped
  u16*    vT   = (u16*)(w + (40u << 20));     // 2 MB  v^T bf16 (512x2048)
  u16*    attn = (u16*)(w + (42u << 20));     // 8 MB  attention out bf16
  (void)ws_size; (void)in_sizes; (void)n_in; (void)out_size;

  cast_all_kernel<<<14848, 256, 0, stream>>>(x, Wq, Wk, Wv, Wo, xb, Wcat, Wob, tab);

  gemm_bt_kernel<false, 2><<<dim3(NQKV/128, S_LEN/64), 256, 0, stream>>>(
      xb, Wcat, nullptr, nullptr, tab, qb, kb, vT, S_LEN, NQKV, E_DIM);

  attn_kernel<<<512, 256, 0, stream>>>(qb, kb, vT, attn);

  gemm_bt_kernel<true, 0><<<dim3(E_DIM/128, S_LEN/64), 256, 0, stream>>>(
      attn, Wob, out, bo, nullptr, nullptr, nullptr, nullptr, S_LEN, E_DIM, E_DIM);
}

// Round 14
// 130.064 us; speedup vs baseline: 1.3336x; 1.0287x over previous
//
#include <hip/hip_runtime.h>
#include <stdint.h>

typedef unsigned short u16;
typedef float  f32x4  __attribute__((ext_vector_type(4)));
typedef float  f32x16 __attribute__((ext_vector_type(16)));
typedef __bf16 bf16x8 __attribute__((ext_vector_type(8)));
typedef __bf16 bf16x4 __attribute__((ext_vector_type(4)));
typedef unsigned short u16x8 __attribute__((ext_vector_type(8)));
typedef unsigned short u16x4v __attribute__((ext_vector_type(4)));
typedef unsigned int u32x2 __attribute__((ext_vector_type(2)));
typedef unsigned int u32x4 __attribute__((ext_vector_type(4)));

#define S_LEN 2048
#define E_DIM 2048
#define HD    128
#define QH    16
#define KVH   4
#define KVD   512
#define NQKV  3072
#define QK_SCALE 0.08838834764831845f  // 1/sqrt(128)

#define AS1 __attribute__((address_space(1)))
#define AS3 __attribute__((address_space(3)))

__device__ __forceinline__ u16 f2bf(float f) {
  union { float f; uint32_t u; } v; v.f = f;
  return (u16)((v.u + 0x7FFFu + ((v.u >> 16) & 1u)) >> 16);
}

// ---------------- fused cast fp32->bf16 (5 tensors) + RoPE trig table ----------
__global__ void cast_all_kernel(const float* __restrict__ x, const float* __restrict__ Wq,
                                const float* __restrict__ Wk, const float* __restrict__ Wv,
                                const float* __restrict__ Wo,
                                u16* __restrict__ xb, u16* __restrict__ Wcat,
                                u16* __restrict__ Wob, float2* __restrict__ tab) {
  int i = blockIdx.x * blockDim.x + threadIdx.x;
  if (i >= 3670016) {           // rope table
    int j = i - 3670016;        // 0 .. 131071
    int s = j >> 6, pidx = j & 63;
    float inv = exp2f((float)pidx * (-13.287712379549449f / 64.0f));  // 10000^(-p/64)
    float sn, cs;
    sincosf((float)s * inv, &sn, &cs);
    tab[j] = make_float2(cs, sn);
    return;
  }
  const float* src; u16* dst;
  if (i < (1 << 20))                       { src = x  + (size_t)i * 4;  dst = xb + (size_t)i * 4; }
  else if (i < (2 << 20))                  { size_t j = i - (1 << 20);  src = Wq + j * 4; dst = Wcat + j * 4; }
  else if (i < (2 << 20) + (1 << 18))      { size_t j = i - (2 << 20);  src = Wk + j * 4; dst = Wcat + (size_t)E_DIM * E_DIM + j * 4; }
  else if (i < (2 << 20) + (2 << 18))      { size_t j = i - (2 << 20) - (1 << 18); src = Wv + j * 4; dst = Wcat + (size_t)(E_DIM + KVD) * E_DIM + j * 4; }
  else                                     { size_t j = i - (2 << 20) - (2 << 18); src = Wo + j * 4; dst = Wob + j * 4; }
  float4 f = *reinterpret_cast<const float4*>(src);
  u16x4v o;
  o[0] = f2bf(f.x); o[1] = f2bf(f.y); o[2] = f2bf(f.z); o[3] = f2bf(f.w);
  *reinterpret_cast<u16x4v*>(dst) = o;
}

// ---------------- GEMM: C[M,N] = A[M,K] * B[N,K]^T, bf16 in -------------------
// 64x128 tile (M x N), BK=64, 256 threads = 4 waves (each owns 64x32).
// MODE 0: fp32 C + bias.  MODE 2: fused QKV epilogue (RoPE + V-transpose).
template<bool BIAS, int MODE>
__global__ __launch_bounds__(256) void gemm_bt_kernel(
    const u16* __restrict__ A, const u16* __restrict__ B,
    float* __restrict__ C, const float* __restrict__ bias,
    const float2* __restrict__ tab, u16* __restrict__ qb,
    u16* __restrict__ kb, u16* __restrict__ vTp,
    int M, int N, int K)
{
  __shared__ u16 As[2][64 * 64];    // 8 KB x2
  __shared__ u16 Bs[2][128 * 64];   // 16 KB x2

  const int tid  = threadIdx.x;
  const int lane = tid & 63;
  const int wid  = tid >> 6;        // 0..3
  const int wc   = wid * 32;
  const int lr   = lane & 15;
  const int kg   = lane >> 4;
  const int sw   = lr & 7;

  const int bm = blockIdx.y * 64;
  const int bn = blockIdx.x * 128;

  f32x4 acc[4][2];
  #pragma unroll
  for (int r = 0; r < 4; ++r)
    #pragma unroll
    for (int c = 0; c < 2; ++c) acc[r][c] = (f32x4){0.f, 0.f, 0.f, 0.f};

  const int srow   = wid * 8 + (lane >> 3);
  const int schunk = (lane & 7) ^ (lane >> 3);

  const u16* gA = A + (size_t)(bm + srow) * K + schunk * 8;
  const u16* gB = B + (size_t)(bn + srow) * K + schunk * 8;

  auto stage = [&](int buf, int kt) {
    #pragma unroll
    for (int i = 0; i < 2; ++i)
      __builtin_amdgcn_global_load_lds(
          (const AS1 void*)(gA + (size_t)i * 32 * K + kt),
          (AS3 void*)(&As[buf][(wid*8 + i*32) * 64]), 16, 0, 0);
    #pragma unroll
    for (int i = 0; i < 4; ++i)
      __builtin_amdgcn_global_load_lds(
          (const AS1 void*)(gB + (size_t)i * 32 * K + kt),
          (AS3 void*)(&Bs[buf][(wid*8 + i*32) * 64]), 16, 0, 0);
  };

  stage(0, 0);
  __syncthreads();

  int cur = 0;
  for (int kt = 0; kt < K; kt += 64) {
    if (kt + 64 < K) stage(cur ^ 1, kt + 64);
    #pragma unroll
    for (int kk = 0; kk < 2; ++kk) {
      bf16x8 af[4], bfr[2];
      #pragma unroll
      for (int r = 0; r < 4; ++r)
        af[r] = *reinterpret_cast<const bf16x8*>(
            &As[cur][(r*16 + lr)*64 + ((kk*4 + kg) ^ sw)*8]);
      #pragma unroll
      for (int c = 0; c < 2; ++c)
        bfr[c] = *reinterpret_cast<const bf16x8*>(
            &Bs[cur][(wc + c*16 + lr)*64 + ((kk*4 + kg) ^ sw)*8]);
      #pragma unroll
      for (int r = 0; r < 4; ++r)
        #pragma unroll
        for (int c = 0; c < 2; ++c)
          acc[r][c] = __builtin_amdgcn_mfma_f32_16x16x32_bf16(af[r], bfr[c], acc[r][c], 0, 0, 0);
    }
    __syncthreads();
    cur ^= 1;
  }

  const int crow = kg * 4;
  #pragma unroll
  for (int r = 0; r < 4; ++r) {
    #pragma unroll
    for (int c = 0; c < 2; ++c) {
      int gr = bm + r*16 + crow;
      int gc = bn + wc + c*16 + lr;
      if constexpr (MODE == 0) {
        float badd = BIAS ? bias[gc] : 0.0f;
        #pragma unroll
        for (int reg = 0; reg < 4; ++reg)
          C[(size_t)(gr + reg)*N + gc] = acc[r][c][reg] + badd;
      } else {  // MODE 2: fused QKV epilogue
        if (gc < E_DIM + KVD) {
          int pidx = (gc & 127) >> 1;
          bool odd = lr & 1;
          #pragma unroll
          for (int reg = 0; reg < 4; ++reg) {
            float val = acc[r][c][reg];
            float oth = __shfl_xor(val, 1);
            float2 cs = tab[(gr + reg) * 64 + pidx];
            float o = odd ? (oth * cs.y + val * cs.x)
                          : (val * cs.x - oth * cs.y);
            if (gc < E_DIM)
              qb[(size_t)(gr + reg) * E_DIM + gc] = f2bf(o * QK_SCALE);
            else
              kb[(size_t)(gr + reg) * KVD + (gc - E_DIM)] = f2bf(o);
          }
        } else {
          bf16x4 pk;
          #pragma unroll
          for (int reg = 0; reg < 4; ++reg) pk[reg] = (__bf16)acc[r][c][reg];
          *reinterpret_cast<bf16x4*>(
              &vTp[(size_t)(gc - E_DIM - KVD) * S_LEN + gr]) = pk;
        }
      }
    }
  }
}

// ---------------- Flash attention (causal, GQA 4:1) -- 32x32 core, kv-split ----
// 512 blocks (flip-paired qt, r13-proven balance), 256 thr = 4 waves:
// wave w: q-rows (w>>1)*32..+32, kv-half (w&1)*32..+32 of EVERY tile, own
// (m,l,O); one flash-combine merge at end via LDS. 32x32x16 frags (r9-verified
// layouts): per wave per tile only 8+8 b128 frag reads; P reaches A-operand
// in-register via cvt-pack + shfl_xor(.,32) (no Ps LDS). LDS = 64 KB exact.
__global__ __launch_bounds__(256, 2) void attn_kernel(
    const u16* __restrict__ Q, const u16* __restrict__ Kc,
    const u16* __restrict__ VT, u16* __restrict__ Out)
{
  __shared__ u16 Ks[2][64 * 128];   // 32 KB; merge: f32 Obuf 64x128
  __shared__ u16 VTs[2][128 * 64];  // 32 KB; merge: Lm/Ll

  const int x = blockIdx.x;
  int qt, h;
  if (x < 256) { qt = x & 31; h = x >> 5; }
  else         { int xp = x - 256; qt = 31 - (xp & 31); h = 8 + (xp >> 5); }
  const int kvh = h >> 2;
  const int tid  = threadIdx.x;
  const int lane = tid & 63;
  const int wid  = tid >> 6;
  const int kvg  = wid & 1;      // kv-half of each tile
  const int rowg = wid >> 1;     // q-row group (32 rows)
  const int ln   = lane & 31;
  const int hi   = lane >> 5;

  const int NT = qt + 1;

  // Q B-frags: col=q=ln, k = ks*16 + hi*8 + j
  bf16x8 qf[8];
  {
    const u16* qa = Q + (size_t)(qt*64 + rowg*32 + ln) * E_DIM + h * HD + hi * 8;
    #pragma unroll
    for (int ks = 0; ks < 8; ++ks)
      qf[ks] = *reinterpret_cast<const bf16x8*>(qa + ks * 16);
  }

  f32x16 o4[4];
  #pragma unroll
  for (int d = 0; d < 4; ++d)
    #pragma unroll
    for (int r = 0; r < 16; ++r) o4[d][r] = 0.f;
  float mr = -1e30f, ls = 0.f;

  u16x8 kreg[4], vreg[4];
  const u16* kbase = Kc + kvh * HD;
  const u16* vbase = VT + (size_t)(kvh * HD) * S_LEN;

  auto stage_load = [&](int t) {
    #pragma unroll
    for (int i = 0; i < 4; ++i) {
      int c = i * 256 + tid;
      kreg[i] = *reinterpret_cast<const u16x8*>(
          kbase + (size_t)(t*64 + (c >> 4)) * KVD + (c & 15) * 8);
      vreg[i] = *reinterpret_cast<const u16x8*>(
          vbase + (size_t)(c >> 3) * S_LEN + t*64 + (c & 7) * 8);
    }
  };
  auto stage_write = [&](int b) {
    #pragma unroll
    for (int i = 0; i < 4; ++i) {
      int c = i * 256 + tid;
      int kr = c >> 4, kc = c & 15;
      *reinterpret_cast<u16x8*>(&Ks[b][kr*128 + (kc ^ (kr & 7))*8]) = kreg[i];
      int vr = c >> 3, vc = c & 7;
      *reinterpret_cast<u16x8*>(&VTs[b][vr*64 + (vc ^ (vr & 7))*8]) = vreg[i];
    }
  };

  int p = 0;
  stage_load(0);
  stage_write(0);
  __syncthreads();

  const int krow = kvg*32 + ln;   // K A-frag row (kv within tile)

  for (int t = 0; t < NT; ++t) {
    if (t + 1 < NT) stage_load(t + 1);  // latency hides under compute

    // S^T = mfma(K, Q): lane (ln,hi) -> S[kv = kvg*32+4hi+(reg&3)+8(reg>>2)][q=ln]
    f32x16 st;
    #pragma unroll
    for (int r = 0; r < 16; ++r) st[r] = 0.f;
    __builtin_amdgcn_s_setprio(1);
    #pragma unroll
    for (int ks = 0; ks < 8; ++ks) {
      bf16x8 kfr = *reinterpret_cast<const bf16x8*>(
          &Ks[p][krow*128 + ((ks*2 + hi) ^ (ln & 7))*8]);
      st = __builtin_amdgcn_mfma_f32_32x32x16_bf16(kfr, qf[ks], st, 0, 0, 0);
    }
    __builtin_amdgcn_s_setprio(0);

    if (t == qt) {  // causal mask on diagonal tile
      #pragma unroll
      for (int reg = 0; reg < 16; ++reg) {
        int kvl = kvg*32 + 4*hi + (reg & 3) + 8*(reg >> 2);
        if (kvl > rowg*32 + ln) st[reg] = -1e30f;
      }
    }

    // row max for q=ln over this wave's 32 kv: in-reg tree + 1 cross-hi shfl
    float pm = -1e30f;
    #pragma unroll
    for (int reg = 0; reg < 16; ++reg) pm = fmaxf(pm, st[reg]);
    pm = fmaxf(pm, __shfl_xor(pm, 32));

    if (!__all(pm - mr <= 8.0f)) {  // defer-max rescale (rare)
      float nm = fmaxf(mr, pm);
      float alpha = __expf(mr - nm);
      ls *= alpha;
      mr = nm;
      #pragma unroll
      for (int reg = 0; reg < 16; ++reg) {
        int crow = (reg & 3) + 8*(reg >> 2) + 4*hi;
        float ar = __shfl(alpha, crow);
        #pragma unroll
        for (int d = 0; d < 4; ++d) o4[d][reg] *= ar;
      }
    }

    float pv[16];
    float sum = 0.f;
    #pragma unroll
    for (int reg = 0; reg < 16; ++reg) {
      pv[reg] = __expf(st[reg] - mr);
      sum += pv[reg];
    }
    sum += __shfl_xor(sum, 32);
    ls += sum;

    // P -> A-frags in-register: pa[ks] = P[q=ln][kv = ks*16 + hi*8 + 0..7].
    // own groupA (regs 8ks..+3) = kv ks*16+4hi+0..3; groupB (regs 8ks+4..+7)
    // = kv ks*16+8+4hi+0..3. hi=0 sends B / keeps A; hi=1 sends A / keeps B.
    bf16x8 pa[2];
    #pragma unroll
    for (int ks = 0; ks < 2; ++ks) {
      bf16x4 A4, B4;
      #pragma unroll
      for (int j = 0; j < 4; ++j) {
        A4[j] = (__bf16)pv[ks*8 + j];
        B4[j] = (__bf16)pv[ks*8 + 4 + j];
      }
      u32x2 uA = __builtin_bit_cast(u32x2, A4);
      u32x2 uB = __builtin_bit_cast(u32x2, B4);
      unsigned sx = hi ? uA[0] : uB[0];
      unsigned sy = hi ? uA[1] : uB[1];
      unsigned rx = __shfl_xor(sx, 32);
      unsigned ry = __shfl_xor(sy, 32);
      u32x4 w;
      w[0] = hi ? rx : uA[0];
      w[1] = hi ? ry : uA[1];
      w[2] = hi ? uB[0] : rx;
      w[3] = hi ? uB[1] : ry;
      pa[ks] = __builtin_bit_cast(bf16x8, w);
    }

    // O += P * V over this wave's kv-half
    __builtin_amdgcn_s_setprio(1);
    #pragma unroll
    for (int d = 0; d < 4; ++d) {
      int vrow = d*32 + ln;
      #pragma unroll
      for (int ks = 0; ks < 2; ++ks) {
        bf16x8 vb = *reinterpret_cast<const bf16x8*>(
            &VTs[p][vrow*64 + ((kvg*4 + ks*2 + hi) ^ (ln & 7))*8]);
        o4[d] = __builtin_amdgcn_mfma_f32_32x32x16_bf16(pa[ks], vb, o4[d], 0, 0, 0);
      }
    }
    __builtin_amdgcn_s_setprio(0);

    if (t + 1 < NT) {
      stage_write(p ^ 1);  // vmcnt wait lands here, after compute
      __syncthreads();     // single barrier per tile
      p ^= 1;
    }
  }

  // -------- merge kv-halves: kvg=1 publishes, kvg=0 combines + writes --------
  __syncthreads();                         // all reads of Ks/VTs done
  float* Obuf = (float*)&Ks[0][0];         // 64 x 128 f32 = 32 KB exact
  float* Lbuf = (float*)&VTs[0][0];        // Lm[64] | Ll[64]
  if (kvg == 1) {
    if (hi == 0) { Lbuf[rowg*32 + ln] = mr; Lbuf[64 + rowg*32 + ln] = ls; }
    #pragma unroll
    for (int reg = 0; reg < 16; ++reg) {
      int crow = (reg & 3) + 8*(reg >> 2) + 4*hi;
      #pragma unroll
      for (int d = 0; d < 4; ++d)
        Obuf[(rowg*32 + crow)*128 + d*32 + ln] = o4[d][reg];
    }
  }
  __syncthreads();
  if (kvg == 0) {
    float mB = Lbuf[rowg*32 + ln];        // partner stats for q = ln
    float lB = Lbuf[64 + rowg*32 + ln];
    float m  = fmaxf(mr, mB);
    float a0 = __expf(mr - m);
    float a1 = __expf(mB - m);
    float inv = 1.0f / (ls*a0 + lB*a1);
    #pragma unroll
    for (int reg = 0; reg < 16; ++reg) {
      int crow = (reg & 3) + 8*(reg >> 2) + 4*hi;
      float a0r = __shfl(a0, crow);
      float a1r = __shfl(a1, crow);
      float ivr = __shfl(inv, crow);
      int grow = qt*64 + rowg*32 + crow;
      #pragma unroll
      for (int d = 0; d < 4; ++d) {
        float v = (o4[d][reg]*a0r +
                   Obuf[(rowg*32 + crow)*128 + d*32 + ln]*a1r) * ivr;
        Out[(size_t)grow * E_DIM + h * HD + d*32 + ln] =
            __builtin_bit_cast(u16, (__bf16)v);
      }
    }
  }
}

// ---------------- launch ----------------
extern "C" void kernel_launch(void* const* d_in, const int* in_sizes, int n_in,
                              void* d_out, int out_size, void* d_ws, size_t ws_size,
                              hipStream_t stream)
{
  const float* x  = (const float*)d_in[0];
  const float* Wq = (const float*)d_in[1];
  const float* Wk = (const float*)d_in[2];
  const float* Wv = (const float*)d_in[3];
  const float* Wo = (const float*)d_in[4];
  const float* bo = (const float*)d_in[5];
  float* out = (float*)d_out;

  char* w = (char*)d_ws;
  u16*    xb   = (u16*)(w);                   // 8 MB  x bf16 (2048x2048)
  u16*    Wcat = (u16*)(w + (8u  << 20));     // 12 MB [Wq;Wk;Wv] bf16 (3072x2048)
  u16*    Wob  = (u16*)(w + (20u << 20));     // 8 MB  Wo bf16
  float2* tab  = (float2*)(w + (28u << 20));  // 1 MB  rope table (2048x64)
  u16*    qb   = (u16*)(w + (30u << 20));     // 8 MB  q bf16 roped+scaled
  u16*    kb   = (u16*)(w + (38u << 20));     // 2 MB  k bf16 roped
  u16*    vT   = (u16*)(w + (40u << 20));     // 2 MB  v^T bf16 (512x2048)
  u16*    attn = (u16*)(w + (42u << 20));     // 8 MB  attention out bf16
  (void)ws_size; (void)in_sizes; (void)n_in; (void)out_size;

  cast_all_kernel<<<14848, 256, 0, stream>>>(x, Wq, Wk, Wv, Wo, xb, Wcat, Wob, tab);

  gemm_bt_kernel<false, 2><<<dim3(NQKV/128, S_LEN/64), 256, 0, stream>>>(
      xb, Wcat, nullptr, nullptr, tab, qb, kb, vT, S_LEN, NQKV, E_DIM);

  attn_kernel<<<512, 256, 0, stream>>>(qb, kb, vT, attn);

  gemm_bt_kernel<true, 0><<<dim3(E_DIM/128, S_LEN/64), 256, 0, stream>>>(
      attn, Wob, out, bo, nullptr, nullptr, nullptr, nullptr, S_LEN, E_DIM, E_DIM);
}